// Round 19
// baseline (565.804 us; speedup 1.0000x reference)
//
#include <hip/hip_runtime.h>
#include <hip/hip_bf16.h>

#define NN 50000
#define NPAD 50048   // 391 * 128
#define NR 8
#define NE 400000
#define PCAP 16      // primary bucket: 16 x 2B = 32B
#define OCAP 16      // overflow bucket: slots 16..31 (cold region)
#define NRANGE 6250  // NN / 8 node-range per XCD slice
#define FCH 8192     // pass-A chunk (edges per bin block)
#define FBLK 392     // 8 rels * 49 chunks
#define XBLK 12500   // NN*64/256 conversion blocks for x
#define TBLK 144     // 9 segs * 16 (64x64) transpose tiles for W
#define QCAP 56320   // per-(rel,range) queue capacity (mean 50000, +30 sigma)

typedef __attribute__((ext_vector_type(8))) short short8v;
typedef __attribute__((ext_vector_type(4))) float f32x4;
typedef __attribute__((ext_vector_type(2))) unsigned int uint2v;

static __device__ __forceinline__ ushort f2b(float f) {
  union { float f; unsigned u; } v; v.f = f;
  unsigned u = v.u;
  unsigned r = (u + 0x7fffu + ((u >> 16) & 1u)) >> 16;
  return (ushort)r;
}
static __device__ __forceinline__ float b2f(ushort u) {
  union { unsigned u; float f; } v; v.u = ((unsigned)u) << 16;
  return v.f;
}

// ---------------- merged prep: edge binning (pass A), x->bf16, W->bf16 transpose ----------------
// Pass A: each (rel, 8192-edge chunk) block reads edges ONCE, histograms the 8
// dst-ranges in LDS, reserves queue space (1 atomic/range/block), appends packed
// (d<<16)|s entries to 64 per-(rel,range) queues. Replaces the 8x-redundant
// range-filtered edge streaming (409MB -> 64MB fabric).

__global__ __launch_bounds__(256) void k_prep(const float* __restrict__ x,
                                              const float* __restrict__ w,
                                              const float* __restrict__ lw,
                                              ushort* __restrict__ xb,
                                              ushort* __restrict__ wb,
                                              const int* __restrict__ src,
                                              const int* __restrict__ dst,
                                              int* __restrict__ qcnt,
                                              unsigned* __restrict__ q) {
  __shared__ ushort tile[64][66];  // W-transpose buffer (separate branch)
  __shared__ int lcnt[8];
  __shared__ int lbase[8];
  int b = blockIdx.x;
  int t = threadIdx.x;
  if (b < FBLK) {
    // ---- pass-A binning ----
    int r = b / 49, c = b % 49;
    const int* dr = dst + (size_t)r * NE;
    const int* sr = src + (size_t)r * NE;
    int e0 = c * FCH;
    if (t < 8) lcnt[t] = 0;
    __syncthreads();
    #pragma unroll 4
    for (int it = 0; it < FCH / 256; ++it) {
      int e = e0 + it * 256 + t;
      if (e < NE) atomicAdd(&lcnt[dr[e] / NRANGE], 1);
    }
    __syncthreads();
    if (t < 8) {
      lbase[t] = atomicAdd(&qcnt[r * 8 + t], lcnt[t]);
      lcnt[t] = 0;
    }
    __syncthreads();
    #pragma unroll 4
    for (int it = 0; it < FCH / 256; ++it) {
      int e = e0 + it * 256 + t;
      if (e < NE) {
        int d = dr[e], s = sr[e];
        int g = d / NRANGE;
        int p = atomicAdd(&lcnt[g], 1);
        int pos = lbase[g] + p;
        if (pos < QCAP)
          q[((size_t)r * 8 + g) * QCAP + pos] = ((unsigned)d << 16) | (unsigned)s;
      }
    }
    return;
  }
  b -= FBLK;
  if (b < XBLK) {
    int i = b * 256 + t;  // one float4 per thread
    float4 v = ((const float4*)x)[i];
    ushort4 o;
    o.x = f2b(v.x); o.y = f2b(v.y); o.z = f2b(v.z); o.w = f2b(v.w);
    ((ushort4*)xb)[i] = o;
    return;
  }
  b -= XBLK;
  {
    // W transpose: 64x64 tile, coalesced loads, coalesced stores.
    int s = b >> 4, t16 = b & 15;
    int kt = (t16 >> 2) * 64, nt2 = (t16 & 3) * 64;
    const float* srcw = (s < 8) ? (w + (size_t)s * 65536) : lw;
    #pragma unroll
    for (int i = 0; i < 16; ++i) {
      int flat = i * 256 + t;
      int kk = flat >> 6, nn = flat & 63;
      tile[kk][nn] = f2b(srcw[(size_t)(kt + kk) * 256 + nt2 + nn]);
    }
    __syncthreads();
    #pragma unroll
    for (int i = 0; i < 16; ++i) {
      int flat = i * 256 + t;
      int nn2 = flat >> 6, kk2 = flat & 63;
      wb[(size_t)s * 65536 + (size_t)(nt2 + nn2) * 256 + kt + kk2] = tile[kk2][nn2];
    }
  }
}

// ---------------- pass B: queue -> split buckets, range -> XCD pinned ----------------

__global__ __launch_bounds__(256) void k_scat(const unsigned* __restrict__ q,
                                              const int* __restrict__ qcnt,
                                              int* __restrict__ cnt,
                                              ushort* __restrict__ csrp,
                                              ushort* __restrict__ ovf) {
  int g = blockIdx.x & 7;           // range -> XCD via round-robin bid mapping
  int idx = blockIdx.x >> 3;        // 0..63
  int r = idx & 7, part = idx >> 3; // 8 parts per (rel, range)
  int total = min(qcnt[r * 8 + g], QCAP);
  int span = (total + 7) / 8;
  int start = part * span, end = min(total, start + span);
  const unsigned* myq = q + ((size_t)r * 8 + g) * QCAP;
  for (int e = start + (int)threadIdx.x; e < end; e += 256) {
    unsigned v = myq[e];
    int d = v >> 16, s = v & 0xFFFF;
    int slot = atomicAdd(&cnt[r * NN + d], 1);
    if (slot < PCAP)
      csrp[((size_t)r * NN + d) * PCAP + slot] = (ushort)s;
    else if (slot < PCAP + OCAP)
      ovf[((size_t)r * NN + d) * OCAP + (slot - PCAP)] = (ushort)s;
  }
}

// ---------------- aggregation: one wave per (node, rel), unroll-4, nt stores ----------------

__global__ __launch_bounds__(256) void k_agg(const ushort* __restrict__ xb,
                                             const ushort* __restrict__ csrp,
                                             const ushort* __restrict__ ovf,
                                             const int* __restrict__ cnt,
                                             ushort* __restrict__ xa,
                                             long strideR, int r0) {
  int wid = threadIdx.x >> 6, lane = threadIdx.x & 63;
  int n = blockIdx.x * 4 + wid;
  int r = r0 + blockIdx.y;
  if (n >= NN) return;
  int dg = cnt[r * NN + n];
  int m = min(dg, PCAP + OCAP);
  int m1 = min(m, PCAP);
  const ushort* lst = csrp + ((size_t)r * NN + n) * PCAP;
  float a0 = 0.f, a1 = 0.f, a2 = 0.f, a3 = 0.f;
  int j = 0;
  for (; j + 3 < m1; j += 4) {
    int s0 = lst[j], s1 = lst[j + 1], s2 = lst[j + 2], s3 = lst[j + 3];
    ushort4 v0 = *(const ushort4*)(xb + (size_t)s0 * 256 + lane * 4);
    ushort4 v1 = *(const ushort4*)(xb + (size_t)s1 * 256 + lane * 4);
    ushort4 v2 = *(const ushort4*)(xb + (size_t)s2 * 256 + lane * 4);
    ushort4 v3 = *(const ushort4*)(xb + (size_t)s3 * 256 + lane * 4);
    a0 += (b2f(v0.x) + b2f(v1.x)) + (b2f(v2.x) + b2f(v3.x));
    a1 += (b2f(v0.y) + b2f(v1.y)) + (b2f(v2.y) + b2f(v3.y));
    a2 += (b2f(v0.z) + b2f(v1.z)) + (b2f(v2.z) + b2f(v3.z));
    a3 += (b2f(v0.w) + b2f(v1.w)) + (b2f(v2.w) + b2f(v3.w));
  }
  for (; j < m1; ++j) {
    ushort4 v0 = *(const ushort4*)(xb + (size_t)lst[j] * 256 + lane * 4);
    a0 += b2f(v0.x); a1 += b2f(v0.y); a2 += b2f(v0.z); a3 += b2f(v0.w);
  }
  if (m > PCAP) {  // rare: overflow slots
    const ushort* lst2 = ovf + ((size_t)r * NN + n) * OCAP;
    for (int j2 = 0; j2 < m - PCAP; ++j2) {
      ushort4 v0 = *(const ushort4*)(xb + (size_t)lst2[j2] * 256 + lane * 4);
      a0 += b2f(v0.x); a1 += b2f(v0.y); a2 += b2f(v0.z); a3 += b2f(v0.w);
    }
  }
  float inv = 1.f / (float)max(dg, 1);
  unsigned w0 = ((unsigned)f2b(a0 * inv)) | (((unsigned)f2b(a1 * inv)) << 16);
  unsigned w1 = ((unsigned)f2b(a2 * inv)) | (((unsigned)f2b(a3 * inv)) << 16);
  uint2v o; o[0] = w0; o[1] = w1;
  __builtin_nontemporal_store(o, (uint2v*)(xa + (size_t)(r - r0) * strideR +
                                           (size_t)n * 256 + lane * 4));
}

// ---------------- GEMM (r12 structure): BM=128 x BN=256, counted-vmcnt pipeline ----------------

#define BK 64

__global__ __launch_bounds__(512, 4) void k_gemm(
    const ushort* __restrict__ xa, long strideR, int nseg,
    const ushort* __restrict__ xb8, const ushort* __restrict__ wb, int wseg0,
    const float* __restrict__ bias, float* __restrict__ out, int first, int final_) {
  __shared__ ushort As[2][128 * BK];  // 2 x 16 KB
  __shared__ ushort Bs[256 * BK];     // 32 KB
  int t = threadIdx.x;
  int lane = t & 63, wid = t >> 6;
  int wm = wid >> 2, wn = wid & 3;
  int i0 = blockIdx.x * 128;
  const int NT = nseg * 4;

  f32x4 acc[4][4];
  #pragma unroll
  for (int a = 0; a < 4; ++a)
    #pragma unroll
    for (int b = 0; b < 4; ++b) acc[a][b] = (f32x4){0.f, 0.f, 0.f, 0.f};

#define STAGE_A(stp, buf) do {                                                  \
    int s_ = (stp) >> 2; int kt_ = ((stp) & 3) * 64;                            \
    const ushort* A_ = (wseg0 + s_ < 8) ? (xa + (size_t)s_ * strideR) : xb8;    \
    _Pragma("unroll")                                                           \
    for (int it = 0; it < 2; ++it) {                                            \
      int c = it * 512 + t; int row = c >> 3, sg = c & 7;                       \
      int sgg = sg ^ (row & 7);                                                 \
      const ushort* ga = A_ + (size_t)(i0 + row) * 256 + kt_ + sgg * 8;         \
      __builtin_amdgcn_global_load_lds(                                         \
          (const __attribute__((address_space(1))) unsigned int*)ga,            \
          (__attribute__((address_space(3))) unsigned int*)(As[buf] + c * 8),   \
          16, 0, 0);                                                            \
    } } while (0)

#define STAGE_B(stp) do {                                                       \
    int s_ = (stp) >> 2; int kt_ = ((stp) & 3) * 64;                            \
    const ushort* W_ = wb + (size_t)(wseg0 + s_) * 65536;                       \
    _Pragma("unroll")                                                           \
    for (int it = 0; it < 4; ++it) {                                            \
      int c = it * 512 + t; int row = c >> 3, sg = c & 7;                       \
      int sgg = sg ^ (row & 7);                                                 \
      const ushort* gb = W_ + (size_t)row * 256 + kt_ + sgg * 8;                \
      __builtin_amdgcn_global_load_lds(                                         \
          (const __attribute__((address_space(1))) unsigned int*)gb,            \
          (__attribute__((address_space(3))) unsigned int*)(Bs + c * 8),        \
          16, 0, 0);                                                            \
    } } while (0)

  STAGE_A(0, 0);  // prologue
  int cur = 0;
  #pragma unroll 1
  for (int st = 0; st < NT; ++st) {
    __builtin_amdgcn_s_barrier();  // all waves done reading Bs / As[cur^1]
    STAGE_B(st);
    if (st + 1 < NT) {
      STAGE_A(st + 1, cur ^ 1);
      asm volatile("s_waitcnt vmcnt(2)" ::: "memory");  // A(cur)+B(cur) retired
    } else {
      asm volatile("s_waitcnt vmcnt(0)" ::: "memory");
    }
    __builtin_amdgcn_sched_barrier(0);
    __builtin_amdgcn_s_barrier();  // tiles visible to all waves
    __builtin_amdgcn_sched_barrier(0);
    const ushort* Ac = As[cur];
    #pragma unroll
    for (int kk = 0; kk < 2; ++kk) {
      int ko = kk * 32 + (lane >> 4) * 8;   // ushort offset within row
      int kb = ko * 2;                      // byte offset (16B-aligned)
      short8v a_frag[4], b_frag[4];
      #pragma unroll
      for (int mi = 0; mi < 4; ++mi) {
        int row = wm * 64 + mi * 16 + (lane & 15);
        int ba = row * 128 + (kb ^ ((row & 7) << 4));
        a_frag[mi] = *(const short8v*)((const char*)Ac + ba);
      }
      #pragma unroll
      for (int ni = 0; ni < 4; ++ni) {
        int row = wn * 64 + ni * 16 + (lane & 15);
        int ba = row * 128 + (kb ^ ((row & 7) << 4));
        b_frag[ni] = *(const short8v*)((const char*)Bs + ba);
      }
      #pragma unroll
      for (int mi = 0; mi < 4; ++mi)
        #pragma unroll
        for (int ni = 0; ni < 4; ++ni)
          acc[mi][ni] = __builtin_amdgcn_mfma_f32_16x16x32_bf16(
              a_frag[mi], b_frag[ni], acc[mi][ni], 0, 0, 0);
    }
    cur ^= 1;
  }
#undef STAGE_A
#undef STAGE_B

  // epilogue: C elem (col = lane&15, row = (lane>>4)*4 + reg)
  #pragma unroll
  for (int mi = 0; mi < 4; ++mi) {
    int rbase = i0 + wm * 64 + mi * 16 + ((lane >> 4) << 2);
    #pragma unroll
    for (int ni = 0; ni < 4; ++ni) {
      int col = wn * 64 + ni * 16 + (lane & 15);
      float bv = final_ ? bias[col] : 0.f;
      #pragma unroll
      for (int rg = 0; rg < 4; ++rg) {
        int gm = rbase + rg;
        if (gm < NN) {
          size_t o = (size_t)gm * 256 + col;
          float v = acc[mi][ni][rg];
          if (!first) v += out[o];
          if (final_) v = fmaxf(v + bv, 0.f);
          out[o] = v;
        }
      }
    }
  }
}

// ---------------- host ----------------

extern "C" void kernel_launch(void* const* d_in, const int* in_sizes, int n_in,
                              void* d_out, int out_size, void* d_ws, size_t ws_size,
                              hipStream_t stream) {
  const float* x = (const float*)d_in[0];
  const float* w = (const float*)d_in[1];
  const float* bias = (const float*)d_in[2];
  const float* lw = (const float*)d_in[3];
  const int* src = (const int*)d_in[4];
  const int* dst = (const int*)d_in[5];
  float* out = (float*)d_out;

  char* ws = (char*)d_ws;
  size_t off = 0;
  auto carve = [&](size_t bytes) {
    size_t o = off;
    off = (off + bytes + 255) & ~(size_t)255;
    return o;
  };
  int* cnt = (int*)(ws + carve((size_t)NR * NN * 4));
  int* qcnt = (int*)(ws + carve((size_t)64 * 4));   // contiguous after cnt
  ushort* csrp = (ushort*)(ws + carve((size_t)NR * NN * PCAP * 2));
  ushort* ovf = (ushort*)(ws + carve((size_t)NR * NN * OCAP * 2));
  ushort* wb = (ushort*)(ws + carve((size_t)9 * 65536 * 2));
  ushort* xb = (ushort*)(ws + carve((size_t)NPAD * 256 * 2));
  size_t base_bytes = off;
  ushort* xa = (ushort*)(ws + off);
  unsigned* q = (unsigned*)xa;  // queues overlay xa (dead before agg writes xa)
  const size_t segb = (size_t)NPAD * 256 * 2;
  long strideR = (long)NPAD * 256;

  (void)hipMemsetAsync(cnt, 0, (size_t)NR * NN * 4 + 512, stream);  // cnt + qcnt
  k_prep<<<FBLK + XBLK + TBLK, 256, 0, stream>>>(x, w, lw, xb, wb,
                                                 src, dst, qcnt, q);
  k_scat<<<512, 256, 0, stream>>>(q, qcnt, cnt, csrp, ovf);

  dim3 gemm_grid(NPAD / 128);
  if (ws_size >= base_bytes + 8 * segb) {
    // Tier A: all 8 aggregated segments at once, single GEMM over 9 segs.
    k_agg<<<dim3((NN + 3) / 4, 8), 256, 0, stream>>>(xb, csrp, ovf, cnt, xa, strideR, 0);
    k_gemm<<<gemm_grid, 512, 0, stream>>>(xa, strideR, 9, xb, wb, 0, bias, out, 1, 1);
  } else if (ws_size >= base_bytes + 4 * segb) {
    // Tier B: two 4-segment passes.
    k_agg<<<dim3((NN + 3) / 4, 4), 256, 0, stream>>>(xb, csrp, ovf, cnt, xa, strideR, 0);
    k_gemm<<<gemm_grid, 512, 0, stream>>>(xa, strideR, 4, xb, wb, 0, bias, out, 1, 0);
    k_agg<<<dim3((NN + 3) / 4, 4), 256, 0, stream>>>(xb, csrp, ovf, cnt, xa, strideR, 4);
    k_gemm<<<gemm_grid, 512, 0, stream>>>(xa, strideR, 5, xb, wb, 4, bias, out, 0, 1);
  } else {
    // Tier C: one relation at a time.
    for (int r = 0; r < 8; ++r) {
      k_agg<<<dim3((NN + 3) / 4, 1), 256, 0, stream>>>(xb, csrp, ovf, cnt, xa, strideR, r);
      k_gemm<<<gemm_grid, 512, 0, stream>>>(xa, strideR, 1, xb, wb, r, bias, out,
                                            (r == 0) ? 1 : 0, 0);
    }
    k_gemm<<<gemm_grid, 512, 0, stream>>>(xa, strideR, 1, xb, wb, 8, bias, out, 0, 1);
  }
  (void)in_sizes; (void)n_in; (void)out_size;
}

// Round 20
// 448.537 us; speedup vs baseline: 1.2614x; 1.2614x over previous
//
#include <hip/hip_runtime.h>
#include <hip/hip_bf16.h>

#define NN 50000
#define NPAD 50048   // 391 * 128
#define NR 8
#define NE 400000
#define PCAP 16      // primary bucket: 16 x 2B = 32B
#define OCAP 16      // overflow bucket: slots 16..31 (cold region)
#define CHUNK 2048
#define CPB 196      // ceil(NE / CHUNK)
#define RSPAN 12500  // NN / 4 node-range per XCD-pair
#define XBLK 12500   // NN*64/256 conversion blocks for x
#define TBLK 144     // 9 segs * 16 (64x64) transpose tiles for W

typedef __attribute__((ext_vector_type(8))) short short8v;
typedef __attribute__((ext_vector_type(4))) float f32x4;
typedef __attribute__((ext_vector_type(2))) unsigned int uint2v;

static __device__ __forceinline__ ushort f2b(float f) {
  union { float f; unsigned u; } v; v.f = f;
  unsigned u = v.u;
  unsigned r = (u + 0x7fffu + ((u >> 16) & 1u)) >> 16;
  return (ushort)r;
}
static __device__ __forceinline__ float b2f(ushort u) {
  union { unsigned u; float f; } v; v.u = ((unsigned)u) << 16;
  return v.f;
}

// ---------------- merged prep: x->bf16, W->bf16 [seg][n][k] (LDS transpose), CSR fill ----------------
// Fill partition: 4 node-ranges x XCD-pairs. xcd = bid&7; range g = xcd>>1 owns nodes
// [g*12500, (g+1)*12500); half h = xcd&1 takes half of each 2048-edge chunk. Edge
// stream redundancy drops 8x -> 4x (409 -> 205 MB); each range's bucket slice (6.4MB)
// lives across its pair's two L2s. Same-line stores from the two XCDs hit different
// bytes (unique atomic slot) -> safe under byte-masked writebacks (r6 precedent).

__global__ __launch_bounds__(256) void k_prep(const float* __restrict__ x,
                                              const float* __restrict__ w,
                                              const float* __restrict__ lw,
                                              ushort* __restrict__ xb,
                                              ushort* __restrict__ wb,
                                              const int* __restrict__ src,
                                              const int* __restrict__ dst,
                                              int* __restrict__ cnt,
                                              ushort* __restrict__ csrp,
                                              ushort* __restrict__ ovf) {
  __shared__ ushort tile[64][66];  // pitch 66: transposed read stride 33 dwords (conflict-free)
  int b = blockIdx.x;
  if (b < XBLK) {
    int i = b * 256 + threadIdx.x;  // one float4 per thread
    float4 v = ((const float4*)x)[i];
    ushort4 o;
    o.x = f2b(v.x); o.y = f2b(v.y); o.z = f2b(v.z); o.w = f2b(v.w);
    ((ushort4*)xb)[i] = o;
    return;
  }
  if (b < XBLK + TBLK) {
    // W transpose: 64x64 tile, coalesced loads, coalesced stores.
    int tb = b - XBLK;
    int s = tb >> 4, t16 = tb & 15;
    int kt = (t16 >> 2) * 64, nt2 = (t16 & 3) * 64;
    const float* srcw = (s < 8) ? (w + (size_t)s * 65536) : lw;
    int t = threadIdx.x;
    #pragma unroll
    for (int i = 0; i < 16; ++i) {
      int flat = i * 256 + t;
      int kk = flat >> 6, nn = flat & 63;
      tile[kk][nn] = f2b(srcw[(size_t)(kt + kk) * 256 + nt2 + nn]);
    }
    __syncthreads();
    #pragma unroll
    for (int i = 0; i < 16; ++i) {
      int flat = i * 256 + t;
      int nn2 = flat >> 6, kk2 = flat & 63;
      wb[(size_t)s * 65536 + (size_t)(nt2 + nn2) * 256 + kt + kk2] = tile[kk2][nn2];
    }
    return;
  }
  // CSR fill: xcd = GLOBAL bid parity; range = xcd>>1, half-chunk = xcd&1.
  int xcd = b & 7;
  int g = xcd >> 1, h = xcd & 1;
  int rc = (b - XBLK - TBLK) >> 3;
  int r = rc / CPB;
  int c = rc - r * CPB;
  int nlo = g * RSPAN, nhi = nlo + RSPAN;
  const int* dr = dst + (size_t)r * NE;
  const int* sr = src + (size_t)r * NE;
  int e = c * CHUNK + h * (CHUNK / 2) + threadIdx.x * 4;  // 1024 edges per block
  if (e + 3 < NE) {
    int4 d4 = *(const int4*)(dr + e);
    int4 s4 = *(const int4*)(sr + e);
    #pragma unroll
    for (int k = 0; k < 4; ++k) {
      int d = (k == 0) ? d4.x : (k == 1) ? d4.y : (k == 2) ? d4.z : d4.w;
      int s = (k == 0) ? s4.x : (k == 1) ? s4.y : (k == 2) ? s4.z : s4.w;
      if (d >= nlo && d < nhi) {
        int slot = atomicAdd(&cnt[r * NN + d], 1);
        if (slot < PCAP)
          csrp[((size_t)r * NN + d) * PCAP + slot] = (ushort)s;
        else if (slot < PCAP + OCAP)
          ovf[((size_t)r * NN + d) * OCAP + (slot - PCAP)] = (ushort)s;
      }
    }
  } else {
    for (int k = 0; k < 4; ++k) {
      int e2 = e + k;
      if (e2 < NE) {
        int d = dr[e2];
        if (d >= nlo && d < nhi) {
          int slot = atomicAdd(&cnt[r * NN + d], 1);
          if (slot < PCAP)
            csrp[((size_t)r * NN + d) * PCAP + slot] = (ushort)sr[e2];
          else if (slot < PCAP + OCAP)
            ovf[((size_t)r * NN + d) * OCAP + (slot - PCAP)] = (ushort)sr[e2];
        }
      }
    }
  }
}

// ---------------- aggregation: one wave per (node, rel), unroll-4, nt stores ----------------

__global__ __launch_bounds__(256) void k_agg(const ushort* __restrict__ xb,
                                             const ushort* __restrict__ csrp,
                                             const ushort* __restrict__ ovf,
                                             const int* __restrict__ cnt,
                                             ushort* __restrict__ xa,
                                             long strideR, int r0) {
  int wid = threadIdx.x >> 6, lane = threadIdx.x & 63;
  int n = blockIdx.x * 4 + wid;
  int r = r0 + blockIdx.y;
  if (n >= NN) return;
  int dg = cnt[r * NN + n];
  int m = min(dg, PCAP + OCAP);
  int m1 = min(m, PCAP);
  const ushort* lst = csrp + ((size_t)r * NN + n) * PCAP;
  float a0 = 0.f, a1 = 0.f, a2 = 0.f, a3 = 0.f;
  int j = 0;
  for (; j + 3 < m1; j += 4) {
    int s0 = lst[j], s1 = lst[j + 1], s2 = lst[j + 2], s3 = lst[j + 3];
    ushort4 v0 = *(const ushort4*)(xb + (size_t)s0 * 256 + lane * 4);
    ushort4 v1 = *(const ushort4*)(xb + (size_t)s1 * 256 + lane * 4);
    ushort4 v2 = *(const ushort4*)(xb + (size_t)s2 * 256 + lane * 4);
    ushort4 v3 = *(const ushort4*)(xb + (size_t)s3 * 256 + lane * 4);
    a0 += (b2f(v0.x) + b2f(v1.x)) + (b2f(v2.x) + b2f(v3.x));
    a1 += (b2f(v0.y) + b2f(v1.y)) + (b2f(v2.y) + b2f(v3.y));
    a2 += (b2f(v0.z) + b2f(v1.z)) + (b2f(v2.z) + b2f(v3.z));
    a3 += (b2f(v0.w) + b2f(v1.w)) + (b2f(v2.w) + b2f(v3.w));
  }
  for (; j < m1; ++j) {
    ushort4 v0 = *(const ushort4*)(xb + (size_t)lst[j] * 256 + lane * 4);
    a0 += b2f(v0.x); a1 += b2f(v0.y); a2 += b2f(v0.z); a3 += b2f(v0.w);
  }
  if (m > PCAP) {  // rare: overflow slots
    const ushort* lst2 = ovf + ((size_t)r * NN + n) * OCAP;
    for (int j2 = 0; j2 < m - PCAP; ++j2) {
      ushort4 v0 = *(const ushort4*)(xb + (size_t)lst2[j2] * 256 + lane * 4);
      a0 += b2f(v0.x); a1 += b2f(v0.y); a2 += b2f(v0.z); a3 += b2f(v0.w);
    }
  }
  float inv = 1.f / (float)max(dg, 1);
  unsigned w0 = ((unsigned)f2b(a0 * inv)) | (((unsigned)f2b(a1 * inv)) << 16);
  unsigned w1 = ((unsigned)f2b(a2 * inv)) | (((unsigned)f2b(a3 * inv)) << 16);
  uint2v o; o[0] = w0; o[1] = w1;
  __builtin_nontemporal_store(o, (uint2v*)(xa + (size_t)(r - r0) * strideR +
                                           (size_t)n * 256 + lane * 4));
}

// ---------------- GEMM (r12 structure): BM=128 x BN=256, counted-vmcnt pipeline ----------------
// A dbuf 2x16KB + Bs 32KB = 64KB, 2 blocks/CU. Both-sides XOR swizzle (r8-verified).

#define BK 64

__global__ __launch_bounds__(512, 4) void k_gemm(
    const ushort* __restrict__ xa, long strideR, int nseg,
    const ushort* __restrict__ xb8, const ushort* __restrict__ wb, int wseg0,
    const float* __restrict__ bias, float* __restrict__ out, int first, int final_) {
  __shared__ ushort As[2][128 * BK];  // 2 x 16 KB
  __shared__ ushort Bs[256 * BK];     // 32 KB
  int t = threadIdx.x;
  int lane = t & 63, wid = t >> 6;
  int wm = wid >> 2, wn = wid & 3;
  int i0 = blockIdx.x * 128;
  const int NT = nseg * 4;

  f32x4 acc[4][4];
  #pragma unroll
  for (int a = 0; a < 4; ++a)
    #pragma unroll
    for (int b = 0; b < 4; ++b) acc[a][b] = (f32x4){0.f, 0.f, 0.f, 0.f};

#define STAGE_A(stp, buf) do {                                                  \
    int s_ = (stp) >> 2; int kt_ = ((stp) & 3) * 64;                            \
    const ushort* A_ = (wseg0 + s_ < 8) ? (xa + (size_t)s_ * strideR) : xb8;    \
    _Pragma("unroll")                                                           \
    for (int it = 0; it < 2; ++it) {                                            \
      int c = it * 512 + t; int row = c >> 3, sg = c & 7;                       \
      int sgg = sg ^ (row & 7);                                                 \
      const ushort* ga = A_ + (size_t)(i0 + row) * 256 + kt_ + sgg * 8;         \
      __builtin_amdgcn_global_load_lds(                                         \
          (const __attribute__((address_space(1))) unsigned int*)ga,            \
          (__attribute__((address_space(3))) unsigned int*)(As[buf] + c * 8),   \
          16, 0, 0);                                                            \
    } } while (0)

#define STAGE_B(stp) do {                                                       \
    int s_ = (stp) >> 2; int kt_ = ((stp) & 3) * 64;                            \
    const ushort* W_ = wb + (size_t)(wseg0 + s_) * 65536;                       \
    _Pragma("unroll")                                                           \
    for (int it = 0; it < 4; ++it) {                                            \
      int c = it * 512 + t; int row = c >> 3, sg = c & 7;                       \
      int sgg = sg ^ (row & 7);                                                 \
      const ushort* gb = W_ + (size_t)row * 256 + kt_ + sgg * 8;                \
      __builtin_amdgcn_global_load_lds(                                         \
          (const __attribute__((address_space(1))) unsigned int*)gb,            \
          (__attribute__((address_space(3))) unsigned int*)(Bs + c * 8),        \
          16, 0, 0);                                                            \
    } } while (0)

  STAGE_A(0, 0);  // prologue
  int cur = 0;
  #pragma unroll 1
  for (int st = 0; st < NT; ++st) {
    __builtin_amdgcn_s_barrier();  // all waves done reading Bs / As[cur^1]
    STAGE_B(st);
    if (st + 1 < NT) {
      STAGE_A(st + 1, cur ^ 1);
      asm volatile("s_waitcnt vmcnt(2)" ::: "memory");  // A(cur)+B(cur) retired
    } else {
      asm volatile("s_waitcnt vmcnt(0)" ::: "memory");
    }
    __builtin_amdgcn_sched_barrier(0);
    __builtin_amdgcn_s_barrier();  // tiles visible to all waves
    __builtin_amdgcn_sched_barrier(0);
    const ushort* Ac = As[cur];
    #pragma unroll
    for (int kk = 0; kk < 2; ++kk) {
      int ko = kk * 32 + (lane >> 4) * 8;   // ushort offset within row
      int kb = ko * 2;                      // byte offset (16B-aligned)
      short8v a_frag[4], b_frag[4];
      #pragma unroll
      for (int mi = 0; mi < 4; ++mi) {
        int row = wm * 64 + mi * 16 + (lane & 15);
        int ba = row * 128 + (kb ^ ((row & 7) << 4));
        a_frag[mi] = *(const short8v*)((const char*)Ac + ba);
      }
      #pragma unroll
      for (int ni = 0; ni < 4; ++ni) {
        int row = wn * 64 + ni * 16 + (lane & 15);
        int ba = row * 128 + (kb ^ ((row & 7) << 4));
        b_frag[ni] = *(const short8v*)((const char*)Bs + ba);
      }
      #pragma unroll
      for (int mi = 0; mi < 4; ++mi)
        #pragma unroll
        for (int ni = 0; ni < 4; ++ni)
          acc[mi][ni] = __builtin_amdgcn_mfma_f32_16x16x32_bf16(
              a_frag[mi], b_frag[ni], acc[mi][ni], 0, 0, 0);
    }
    cur ^= 1;
  }
#undef STAGE_A
#undef STAGE_B

  // epilogue: C elem (col = lane&15, row = (lane>>4)*4 + reg)
  #pragma unroll
  for (int mi = 0; mi < 4; ++mi) {
    int rbase = i0 + wm * 64 + mi * 16 + ((lane >> 4) << 2);
    #pragma unroll
    for (int ni = 0; ni < 4; ++ni) {
      int col = wn * 64 + ni * 16 + (lane & 15);
      float bv = final_ ? bias[col] : 0.f;
      #pragma unroll
      for (int rg = 0; rg < 4; ++rg) {
        int gm = rbase + rg;
        if (gm < NN) {
          size_t o = (size_t)gm * 256 + col;
          float v = acc[mi][ni][rg];
          if (!first) v += out[o];
          if (final_) v = fmaxf(v + bv, 0.f);
          out[o] = v;
        }
      }
    }
  }
}

// ---------------- host ----------------

extern "C" void kernel_launch(void* const* d_in, const int* in_sizes, int n_in,
                              void* d_out, int out_size, void* d_ws, size_t ws_size,
                              hipStream_t stream) {
  const float* x = (const float*)d_in[0];
  const float* w = (const float*)d_in[1];
  const float* bias = (const float*)d_in[2];
  const float* lw = (const float*)d_in[3];
  const int* src = (const int*)d_in[4];
  const int* dst = (const int*)d_in[5];
  float* out = (float*)d_out;

  char* ws = (char*)d_ws;
  size_t off = 0;
  auto carve = [&](size_t bytes) {
    size_t o = off;
    off = (off + bytes + 255) & ~(size_t)255;
    return o;
  };
  int* cnt = (int*)(ws + carve((size_t)NR * NN * 4));
  ushort* csrp = (ushort*)(ws + carve((size_t)NR * NN * PCAP * 2));
  ushort* ovf = (ushort*)(ws + carve((size_t)NR * NN * OCAP * 2));
  ushort* wb = (ushort*)(ws + carve((size_t)9 * 65536 * 2));
  ushort* xb = (ushort*)(ws + carve((size_t)NPAD * 256 * 2));
  size_t base_bytes = off;
  ushort* xa = (ushort*)(ws + off);
  const size_t segb = (size_t)NPAD * 256 * 2;
  long strideR = (long)NPAD * 256;

  (void)hipMemsetAsync(cnt, 0, (size_t)NR * NN * 4, stream);
  k_prep<<<XBLK + TBLK + 8 * CPB * NR, 256, 0, stream>>>(x, w, lw, xb, wb,
                                                         src, dst, cnt, csrp, ovf);

  dim3 gemm_grid(NPAD / 128);
  if (ws_size >= base_bytes + 8 * segb) {
    // Tier A: all 8 aggregated segments at once, single GEMM over 9 segs.
    k_agg<<<dim3((NN + 3) / 4, 8), 256, 0, stream>>>(xb, csrp, ovf, cnt, xa, strideR, 0);
    k_gemm<<<gemm_grid, 512, 0, stream>>>(xa, strideR, 9, xb, wb, 0, bias, out, 1, 1);
  } else if (ws_size >= base_bytes + 4 * segb) {
    // Tier B: two 4-segment passes.
    k_agg<<<dim3((NN + 3) / 4, 4), 256, 0, stream>>>(xb, csrp, ovf, cnt, xa, strideR, 0);
    k_gemm<<<gemm_grid, 512, 0, stream>>>(xa, strideR, 4, xb, wb, 0, bias, out, 1, 0);
    k_agg<<<dim3((NN + 3) / 4, 4), 256, 0, stream>>>(xb, csrp, ovf, cnt, xa, strideR, 4);
    k_gemm<<<gemm_grid, 512, 0, stream>>>(xa, strideR, 5, xb, wb, 4, bias, out, 0, 1);
  } else {
    // Tier C: one relation at a time.
    for (int r = 0; r < 8; ++r) {
      k_agg<<<dim3((NN + 3) / 4, 1), 256, 0, stream>>>(xb, csrp, ovf, cnt, xa, strideR, r);
      k_gemm<<<gemm_grid, 512, 0, stream>>>(xa, strideR, 1, xb, wb, r, bias, out,
                                            (r == 0) ? 1 : 0, 0);
    }
    k_gemm<<<gemm_grid, 512, 0, stream>>>(xa, strideR, 1, xb, wb, 8, bias, out, 0, 1);
  }
  (void)in_sizes; (void)n_in; (void)out_size;
}